// Round 14
// baseline (261.918 us; speedup 1.0000x reference)
//
#include <hip/hip_runtime.h>

#define BB 16
#define NN 4096
#define SS 1024
#define KK 32
#define MPTS (BB*SS*KK)      // 524288
#define EPSF 1e-5f
#define CANDCAP 512
#define WNARROW 16

// workspace layout (float offsets)
#define OFF_QP    0                       // B*S*4
#define OFF_P4    (OFF_QP + BB*SS*4)      // B*N*4
#define OFF_ST    (OFF_P4 + BB*NN*4)      // 512 floats zeroed each call
#define OFF_MOM   (OFF_ST)                // 27
#define OFF_S1SUM (OFF_ST+32)             // 64
#define OFF_S1SQ  (OFF_ST+96)             // 64
#define OFF_S2SUM (OFF_ST+160)            // 128
#define OFF_S2SQ  (OFF_ST+288)            // 128
#define OFF_XG    (OFF_ST+1280)           // 6*MPTS channel-major
#define OFF_MAXB  (OFF_XG + 6*MPTS)       // B*S*128
#define OFF_MINB  (OFF_MAXB + BB*SS*128)  // B*S*128
#define OFF_Y1U   (OFF_MINB + BB*SS*128)  // bf16 (ushort) POINT-major [MPTS][64]

typedef __bf16 bf16x8 __attribute__((ext_vector_type(8)));
typedef float f32x4 __attribute__((ext_vector_type(4)));
typedef unsigned int uintx4 __attribute__((ext_vector_type(4)));

__device__ __forceinline__ unsigned rne_bf16(float f){
  unsigned u = __float_as_uint(f);
  return (u + 0x7FFFu + ((u>>16)&1u)) >> 16;   // RNE f32->bf16 (finite, non-NaN)
}

__global__ __launch_bounds__(256) void prep_kernel(
    const float* __restrict__ xyz, const int* __restrict__ fps,
    float* __restrict__ out, float* __restrict__ ws)
{
  const int g = blockIdx.x*256 + threadIdx.x;
  if (g < BB*NN){
    const float* p = xyz + (size_t)g*3;
    float x=p[0], y=p[1], z=p[2];
    float x2 = __fadd_rn(__fadd_rn(__fmul_rn(x,x),__fmul_rn(y,y)),__fmul_rn(z,z));
    *reinterpret_cast<float4*>(ws + OFF_P4 + (size_t)g*4) = make_float4(x,y,z,x2);
  } else {
    int j = g - BB*NN;
    if (j < BB*SS){
      int b = j >> 10;
      int idx = fps[j];
      const float* p = xyz + ((size_t)b*NN + idx)*3;
      float x=p[0], y=p[1], z=p[2];
      out[(size_t)j*3+0]=x; out[(size_t)j*3+1]=y; out[(size_t)j*3+2]=z;
      float q2 = __fadd_rn(__fadd_rn(__fmul_rn(x,x),__fmul_rn(y,y)),__fmul_rn(z,z));
      *reinterpret_cast<float4*>(ws + OFF_QP + (size_t)j*4) = make_float4(x,y,z,q2);
    }
  }
}

// one block per query: exact 32-NN. Wave-local INTERPOLATION search
// (ballot+popc, no barriers in the loop): count(<d) ~ d^1.5 in 3D, so jump
// mid = lo + (hi-lo)*frac^(2/3) -- converges in ~4-7 rounds vs ~25 for
// bisection. Invariant count(<lo) < KK <= count(<hi) kept every round, so
// the union of per-wave brackets is a superset of the global top-32
// regardless of exit round. Compact + exact rank-select finishes.
__global__ __launch_bounds__(256) void knn_group_kernel(
    const float* __restrict__ pts, float* __restrict__ ws)
{
  __shared__ unsigned long long cand[CANDCAP];
  __shared__ int sel[KK];
  __shared__ unsigned sh_mcnt;

  const int bid = blockIdx.x;
  const int b = bid >> 10;
  const int tid = threadIdx.x;

  const float4 q = *reinterpret_cast<const float4*>(ws + OFF_QP + (size_t)bid*4);
  const float qx=q.x, qy=q.y, qz=q.z, q2=q.w;
  const float4* pb = reinterpret_cast<const float4*>(ws + OFF_P4) + (size_t)b*NN;

  float d[16];               // static-indexed only (all loops unrolled)
  #pragma unroll
  for (int j=0;j<16;j++){
    int n = tid + j*256;
    float4 P = pb[n];
    float dot = __fadd_rn(__fadd_rn(__fmul_rn(qx,P.x),__fmul_rn(qy,P.y)),__fmul_rn(qz,P.z));
    d[j] = __fsub_rn(__fadd_rn(q2, P.w), __fmul_rn(2.0f,dot));
  }

  if (tid==0) sh_mcnt = 0;

  // wave [min,max] (12 shuffles)
  float mn = d[0], mx = d[0];
  #pragma unroll
  for (int j=1;j<16;j++){ mn = fminf(mn,d[j]); mx = fmaxf(mx,d[j]); }
  #pragma unroll
  for (int off=32; off>=1; off>>=1){
    mn = fminf(mn, __shfl_xor(mn, off, 64));
    mx = fmaxf(mx, __shfl_xor(mx, off, 64));
  }

  // wave-local bracket: count(d < lo) < KK <= count(d < hi)
  float lo = mn, hi = __int_as_float(0x7F800000);  // +INF
  unsigned clo = 0, chi = 1024;
  int rounds = 0;
  while (chi - clo > WNARROW && rounds < 24){
    float mid;
    if (rounds == 0){
      mid = mx;                              // probe the finite max first
    } else if (rounds < 8){
      // interpolation: count(<x) ~ (x-lo)^(3/2) locally (3D shell volume)
      float frac = (float)(KK - (int)clo) / (float)(chi - clo);
      mid = lo + (hi - lo) * exp2f(0.6666667f * log2f(frac));
    } else {
      mid = 0.5f*lo + 0.5f*hi;               // bisection fallback
    }
    if (!(mid > lo && mid < hi)) mid = 0.5f*lo + 0.5f*hi;
    if (!(mid > lo && mid < hi)) break;      // interval exhausted
    unsigned cnt = 0;
    #pragma unroll
    for (int j=0;j<16;j++)
      cnt += (unsigned)__popcll(__ballot((int)(d[j] < mid)));
    if (cnt >= (unsigned)KK){ hi = mid; chi = cnt; } else { lo = mid; clo = cnt; }
    ++rounds;
  }
  __syncthreads();   // sh_mcnt init visible; all waves bracketed

  // compact: every d < hi_w is a candidate (superset of global top-32)
  #pragma unroll
  for (int j=0;j<16;j++){
    if (d[j] < hi){
      unsigned u = __float_as_uint(d[j]);
      unsigned key = u ^ (unsigned)(((int)u>>31) | (int)0x80000000);
      unsigned p = atomicAdd(&sh_mcnt,1u);
      if (p < CANDCAP) cand[p] = ((unsigned long long)key<<32) | (unsigned)(tid + j*256);
    }
  }
  __syncthreads();
  const unsigned m = (sh_mcnt < CANDCAP) ? sh_mcnt : CANDCAP;
  // exact rank: (key,idx) lexicographic == packed u64 order (top_k tie rule)
  for (unsigned i=tid; i<m; i+=256){
    const unsigned long long ci = cand[i];
    unsigned r = 0;
    #pragma unroll 4
    for (unsigned jj=0; jj<m; ++jj) r += (cand[jj] < ci) ? 1u : 0u;
    if (r < (unsigned)KK) sel[(int)r] = (int)(ci & 0xFFFFFFFFu);
  }
  __syncthreads();

  // gather the 32 neighbors, write grouped input channel-major
  if (tid < KK){
    int n = sel[tid];
    float4 P = pb[n];
    float v6[6];
    v6[0] = P.x-qx; v6[1] = P.y-qy; v6[2] = P.z-qz;
    const float* pt = pts + ((size_t)b*NN + n)*3;
    v6[3] = pt[0]; v6[4] = pt[1]; v6[5] = pt[2];
    size_t pidx = (size_t)bid*KK + tid;
    float* xg = ws + OFF_XG;
    #pragma unroll
    for (int c=0;c<6;c++) xg[(size_t)c*MPTS + pidx] = v6[c];
  }
}

// layer-0 input moments from the stored grouped input (L3-resident)
__global__ __launch_bounds__(256) void mom2_kernel(float* __restrict__ ws)
{
  static const signed char C1[27]={0,1,2,3,4,5, 0,0,0,0,0,0, 1,1,1,1,1, 2,2,2,2, 3,3,3, 4,4, 5};
  static const signed char C2[27]={-1,-1,-1,-1,-1,-1, 0,1,2,3,4,5, 1,2,3,4,5, 2,3,4,5, 3,4,5, 4,5, 5};
  const int mq = blockIdx.x >> 3;
  const int sl = blockIdx.x & 7;
  const float4* xa = reinterpret_cast<const float4*>(ws + OFF_XG + (size_t)C1[mq]*MPTS) + (size_t)sl*(MPTS/32);
  const int c2 = C2[mq];
  float s = 0.f;
  if (c2 < 0){
    for (int i=threadIdx.x; i<MPTS/32; i+=256){
      float4 a = xa[i];
      s += (a.x+a.y)+(a.z+a.w);
    }
  } else {
    const float4* xb = reinterpret_cast<const float4*>(ws + OFF_XG + (size_t)c2*MPTS) + (size_t)sl*(MPTS/32);
    for (int i=threadIdx.x; i<MPTS/32; i+=256){
      float4 a = xa[i]; float4 bq = xb[i];
      s = fmaf(a.x,bq.x,s); s = fmaf(a.y,bq.y,s);
      s = fmaf(a.z,bq.z,s); s = fmaf(a.w,bq.w,s);
    }
  }
  #pragma unroll
  for (int off=32; off>=1; off>>=1) s += __shfl_xor(s,off,64);
  __shared__ float r[4];
  const int lane = threadIdx.x & 63, wv = threadIdx.x >> 6;
  if (lane==0) r[wv]=s;
  __syncthreads();
  if (threadIdx.x==0) atomicAdd(&ws[OFF_MOM+mq], r[0]+r[1]+r[2]+r[3]);
}

// MFMA layer 1 with finalize0 folded into staging: tid<64 computes BN0-folded
// h0 coefs (swf[c][0..5]=sc*w0, [6]=sc*b0+sh) from the 27 moments.
// D[o][p] = W1[o][c]*h0[c][p]; A=W1 (LDS frag order), B=h0 in-register.
// BN1 stats accumulated in-register, reduced here.
__global__ __launch_bounds__(256) void l1_mfma_kernel(
    const float* __restrict__ w0g, const float* __restrict__ b0g,
    const float* __restrict__ g0, const float* __restrict__ t0,
    const float* __restrict__ w1g, const float* __restrict__ b1g,
    float* __restrict__ ws)
{
  __shared__ __align__(16) unsigned short sA1[4096]; // [mt*2+kt][lane][j]
  __shared__ float swf[64*8];
  __shared__ float red[128];
  const int tid = threadIdx.x;
  const int lane = tid & 63;
  const int wv = tid >> 6;
  const int col = lane & 15;
  const int kg = lane >> 4;

  for (int idx=tid; idx<4096; idx+=256){
    int frag = idx>>9, l = (idx>>3)&63, j = idx&7;
    int mt = frag>>1, kt = frag&1;
    int o = mt*16 + (l&15);
    int c = kt*32 + ((l>>4)<<3) + j;
    sA1[idx] = (unsigned short)rne_bf16(w1g[o*64+c]);
  }
  if (tid<64){
    // finalize0: BN0 scale/shift from input moments, folded into h0 coefs
    const float* mom = ws + OFF_MOM;
    float w[6];
    #pragma unroll
    for (int c=0;c<6;c++) w[c] = w0g[tid*6+c];
    float bo = b0g[tid];
    float wS = 0.f;
    #pragma unroll
    for (int c=0;c<6;c++) wS += w[c]*mom[c];
    const float Mf = (float)MPTS;
    float mean = (wS + Mf*bo) / Mf;
    float qsum = 0.f;
    int mi = 6;
    #pragma unroll
    for (int c=0;c<6;c++){
      #pragma unroll
      for (int c2=c;c2<6;c2++){
        float f = (c==c2)?1.f:2.f;
        qsum += f * w[c]*w[c2]*mom[mi];
        mi++;
      }
    }
    float E2  = (qsum + 2.f*bo*wS + Mf*bo*bo) / Mf;
    float var = E2 - mean*mean;
    float sc  = g0[tid] / sqrtf(var + EPSF);
    float sh  = t0[tid] - mean*sc;
    #pragma unroll
    for (int c=0;c<6;c++) swf[tid*8+c] = sc*w[c];
    swf[tid*8+6] = sc*bo + sh;
    swf[tid*8+7] = 0.f;
  }
  if (tid<128) red[tid]=0.f;
  __syncthreads();

  // folded h0 coefs for this lane's 16 channels (c = kt*32 + kg*8 + j)
  float cw0[2][8], cw1[2][8], cw2[2][8], cw3[2][8], cw4[2][8], cw5[2][8], cb[2][8];
  #pragma unroll
  for (int kt=0; kt<2; ++kt){
    #pragma unroll
    for (int j=0;j<8;j++){
      int c = kt*32 + kg*8 + j;
      float4 a4 = *reinterpret_cast<const float4*>(&swf[c*8]);
      float4 b4 = *reinterpret_cast<const float4*>(&swf[c*8 + 4]);
      cw0[kt][j]=a4.x; cw1[kt][j]=a4.y; cw2[kt][j]=a4.z; cw3[kt][j]=a4.w;
      cw4[kt][j]=b4.x; cw5[kt][j]=b4.y; cb[kt][j]=b4.z;
    }
  }
  float b1v[4][4];
  #pragma unroll
  for (int mt=0;mt<4;mt++)
    #pragma unroll
    for (int r=0;r<4;r++) b1v[mt][r] = b1g[mt*16 + kg*4 + r];

  float s1s[4][4], s1q[4][4];
  #pragma unroll
  for (int mt=0;mt<4;mt++)
    #pragma unroll
    for (int r=0;r<4;r++){ s1s[mt][r]=0.f; s1q[mt][r]=0.f; }

  const float* xg = ws + OFF_XG;
  unsigned short* y1 = (unsigned short*)(ws + OFF_Y1U);
  const int pbase = (blockIdx.x*4 + wv)*256;

  for (int it=0; it<16; ++it){
    const size_t p = (size_t)pbase + it*16 + col;
    const float x0 = xg[p];
    const float x1 = xg[MPTS+p];
    const float x2 = xg[2ul*MPTS+p];
    const float x3 = xg[3ul*MPTS+p];
    const float x4 = xg[4ul*MPTS+p];
    const float x5 = xg[5ul*MPTS+p];

    f32x4 acc0 = {0,0,0,0}, acc1 = {0,0,0,0}, acc2 = {0,0,0,0}, acc3 = {0,0,0,0};

    #pragma unroll
    for (int kt=0; kt<2; ++kt){
      float h[8];
      #pragma unroll
      for (int j=0;j<8;j++){
        float y = cb[kt][j];
        y = fmaf(cw0[kt][j],x0,y); y = fmaf(cw1[kt][j],x1,y);
        y = fmaf(cw2[kt][j],x2,y); y = fmaf(cw3[kt][j],x3,y);
        y = fmaf(cw4[kt][j],x4,y); y = fmaf(cw5[kt][j],x5,y);
        h[j] = fmaxf(y, 0.f);
      }
      uintx4 pk;
      pk[0] = rne_bf16(h[0]) | (rne_bf16(h[1])<<16);
      pk[1] = rne_bf16(h[2]) | (rne_bf16(h[3])<<16);
      pk[2] = rne_bf16(h[4]) | (rne_bf16(h[5])<<16);
      pk[3] = rne_bf16(h[6]) | (rne_bf16(h[7])<<16);
      bf16x8 bfrag = __builtin_bit_cast(bf16x8, pk);
      {
        uintx4 au = *reinterpret_cast<const uintx4*>(&sA1[((0*2+kt)*64+lane)*8]);
        acc0 = __builtin_amdgcn_mfma_f32_16x16x32_bf16(__builtin_bit_cast(bf16x8,au), bfrag, acc0, 0,0,0);
      }
      {
        uintx4 au = *reinterpret_cast<const uintx4*>(&sA1[((1*2+kt)*64+lane)*8]);
        acc1 = __builtin_amdgcn_mfma_f32_16x16x32_bf16(__builtin_bit_cast(bf16x8,au), bfrag, acc1, 0,0,0);
      }
      {
        uintx4 au = *reinterpret_cast<const uintx4*>(&sA1[((2*2+kt)*64+lane)*8]);
        acc2 = __builtin_amdgcn_mfma_f32_16x16x32_bf16(__builtin_bit_cast(bf16x8,au), bfrag, acc2, 0,0,0);
      }
      {
        uintx4 au = *reinterpret_cast<const uintx4*>(&sA1[((3*2+kt)*64+lane)*8]);
        acc3 = __builtin_amdgcn_mfma_f32_16x16x32_bf16(__builtin_bit_cast(bf16x8,au), bfrag, acc3, 0,0,0);
      }
    }
    // epilogue: +b1, stats, pack 4 consecutive o -> uint2, store point-major
    #pragma unroll
    for (int mt=0;mt<4;mt++){
      f32x4 a = (mt==0)?acc0:(mt==1)?acc1:(mt==2)?acc2:acc3;
      float v0 = a[0] + b1v[mt][0];
      float v1 = a[1] + b1v[mt][1];
      float v2 = a[2] + b1v[mt][2];
      float v3 = a[3] + b1v[mt][3];
      s1s[mt][0]+=v0; s1q[mt][0]=fmaf(v0,v0,s1q[mt][0]);
      s1s[mt][1]+=v1; s1q[mt][1]=fmaf(v1,v1,s1q[mt][1]);
      s1s[mt][2]+=v2; s1q[mt][2]=fmaf(v2,v2,s1q[mt][2]);
      s1s[mt][3]+=v3; s1q[mt][3]=fmaf(v3,v3,s1q[mt][3]);
      uint2 st;
      st.x = rne_bf16(v0) | (rne_bf16(v1)<<16);
      st.y = rne_bf16(v2) | (rne_bf16(v3)<<16);
      *reinterpret_cast<uint2*>(y1 + p*64 + mt*16 + kg*4) = st;
    }
  }

  // stats: reduce over the 16 col-lanes (bits 0..3 of lane)
  #pragma unroll
  for (int mt=0;mt<4;mt++){
    #pragma unroll
    for (int r=0;r<4;r++){
      float s = s1s[mt][r], qv = s1q[mt][r];
      s += __shfl_xor(s,1,64); s += __shfl_xor(s,2,64);
      s += __shfl_xor(s,4,64); s += __shfl_xor(s,8,64);
      qv += __shfl_xor(qv,1,64); qv += __shfl_xor(qv,2,64);
      qv += __shfl_xor(qv,4,64); qv += __shfl_xor(qv,8,64);
      if (col==0){
        atomicAdd(&red[mt*16 + kg*4 + r], s);
        atomicAdd(&red[64 + mt*16 + kg*4 + r], qv);
      }
    }
  }
  __syncthreads();
  if (tid < 64){
    atomicAdd(&ws[OFF_S1SUM+tid], red[tid]);
    atomicAdd(&ws[OFF_S1SQ+tid],  red[64+tid]);
  }
}

// MFMA layer 2 with finalize1 folded into staging (tid<64 computes sc1/sh1).
// C[512K x 128] = relu(bn1(Y1))[512K x 64] * W2[64 x 128] + b2.
// A-frag: m=lane&15 (point), k=(lane>>4)*8+j; D: col=lane&15, row=(lane>>4)*4+r.
__global__ __launch_bounds__(256) void l2_mfma_kernel(
    const float* __restrict__ w2g, const float* __restrict__ b2g,
    const float* __restrict__ g1, const float* __restrict__ t1,
    float* __restrict__ ws)
{
  __shared__ __align__(16) unsigned short sB[8192]; // [nt][kt][lane][j]
  __shared__ float s1c[64], s1h[64];
  __shared__ float red[256];
  const int tid = threadIdx.x;
  for (int idx=tid; idx<8192; idx+=256){
    int nt = idx>>10, kt = (idx>>9)&1, l = (idx>>3)&63, j = idx&7;
    int kch = kt*32 + ((l>>4)<<3) + j;
    int o   = (nt<<4) + (l&15);
    sB[idx] = (unsigned short)rne_bf16(w2g[o*64+kch]);
  }
  if (tid<64){
    // finalize1: BN1 scale/shift from y1 stats
    const float Mf = (float)MPTS;
    float mean = ws[OFF_S1SUM+tid]/Mf;
    float var  = ws[OFF_S1SQ+tid]/Mf - mean*mean;
    float sc = g1[tid]/sqrtf(var+EPSF);
    s1c[tid]=sc; s1h[tid]=t1[tid]-mean*sc;
  }
  red[tid]=0.f;
  __syncthreads();

  const int lane = tid & 63;
  const int w    = tid >> 6;
  const int col  = lane & 15;
  const int kg   = lane >> 4;    // 0..3

  float scv[2][8], shv[2][8];
  #pragma unroll
  for (int kt=0;kt<2;kt++)
    #pragma unroll
    for (int j=0;j<8;j++){
      scv[kt][j] = s1c[kt*32 + kg*8 + j];
      shv[kt][j] = s1h[kt*32 + kg*8 + j];
    }
  float b2v[8];
  #pragma unroll
  for (int nt=0;nt<8;nt++) b2v[nt] = b2g[nt*16 + col];

  const unsigned short* y1 = (const unsigned short*)(ws + OFF_Y1U);
  float* maxb = ws + OFF_MAXB;
  float* minb = ws + OFF_MINB;

  float sumacc[8], sqacc[8];
  #pragma unroll
  for (int nt=0;nt<8;nt++){ sumacc[nt]=0.f; sqacc[nt]=0.f; }

  const int gbase = (blockIdx.x*4 + w)*4;
  for (int it=0; it<4; ++it){
    const int g = gbase + it;
    const size_t p0 = (size_t)g*32;
    bf16x8 aA[2][2];
    #pragma unroll
    for (int mh=0; mh<2; ++mh){
      const unsigned short* arow = y1 + (p0 + mh*16 + col)*64 + kg*8;
      #pragma unroll
      for (int kt=0; kt<2; ++kt){
        uintx4 ua = *reinterpret_cast<const uintx4*>(arow + kt*32);
        float h0 = fmaxf(fmaf(scv[kt][0], __uint_as_float(ua[0]<<16),          shv[kt][0]), 0.f);
        float h1 = fmaxf(fmaf(scv[kt][1], __uint_as_float(ua[0]&0xFFFF0000u), shv[kt][1]), 0.f);
        float h2 = fmaxf(fmaf(scv[kt][2], __uint_as_float(ua[1]<<16),          shv[kt][2]), 0.f);
        float h3 = fmaxf(fmaf(scv[kt][3], __uint_as_float(ua[1]&0xFFFF0000u), shv[kt][3]), 0.f);
        float h4 = fmaxf(fmaf(scv[kt][4], __uint_as_float(ua[2]<<16),          shv[kt][4]), 0.f);
        float h5 = fmaxf(fmaf(scv[kt][5], __uint_as_float(ua[2]&0xFFFF0000u), shv[kt][5]), 0.f);
        float h6 = fmaxf(fmaf(scv[kt][6], __uint_as_float(ua[3]<<16),          shv[kt][6]), 0.f);
        float h7 = fmaxf(fmaf(scv[kt][7], __uint_as_float(ua[3]&0xFFFF0000u), shv[kt][7]), 0.f);
        uintx4 pk;
        pk[0] = rne_bf16(h0) | (rne_bf16(h1)<<16);
        pk[1] = rne_bf16(h2) | (rne_bf16(h3)<<16);
        pk[2] = rne_bf16(h4) | (rne_bf16(h5)<<16);
        pk[3] = rne_bf16(h6) | (rne_bf16(h7)<<16);
        aA[mh][kt] = __builtin_bit_cast(bf16x8, pk);
      }
    }
    f32x4 acc[2][8];
    #pragma unroll
    for (int mh=0;mh<2;mh++)
      #pragma unroll
      for (int nt=0;nt<8;nt++){
        f32x4 z = {b2v[nt], b2v[nt], b2v[nt], b2v[nt]};
        acc[mh][nt] = z;
      }
    #pragma unroll
    for (int nt=0;nt<8;nt++){
      #pragma unroll
      for (int kt=0;kt<2;kt++){
        uintx4 bu = *reinterpret_cast<const uintx4*>(&sB[((nt*2+kt)*64 + lane)*8]);
        bf16x8 bv = __builtin_bit_cast(bf16x8, bu);
        acc[0][nt] = __builtin_amdgcn_mfma_f32_16x16x32_bf16(aA[0][kt], bv, acc[0][nt], 0,0,0);
        acc[1][nt] = __builtin_amdgcn_mfma_f32_16x16x32_bf16(aA[1][kt], bv, acc[1][nt], 0,0,0);
      }
    }
    #pragma unroll
    for (int nt=0;nt<8;nt++){
      f32x4 a0 = acc[0][nt], a1 = acc[1][nt];
      float mx = fmaxf(fmaxf(fmaxf(a0[0],a0[1]),fmaxf(a0[2],a0[3])),
                       fmaxf(fmaxf(a1[0],a1[1]),fmaxf(a1[2],a1[3])));
      float mn = fminf(fminf(fminf(a0[0],a0[1]),fminf(a0[2],a0[3])),
                       fminf(fminf(a1[0],a1[1]),fminf(a1[2],a1[3])));
      mx = fmaxf(mx, __shfl_xor(mx,16,64)); mx = fmaxf(mx, __shfl_xor(mx,32,64));
      mn = fminf(mn, __shfl_xor(mn,16,64)); mn = fminf(mn, __shfl_xor(mn,32,64));
      float s = ((a0[0]+a0[1])+(a0[2]+a0[3])) + ((a1[0]+a1[1])+(a1[2]+a1[3]));
      sumacc[nt] += s;
      float qv = 0.f;
      qv = fmaf(a0[0],a0[0],qv); qv = fmaf(a0[1],a0[1],qv);
      qv = fmaf(a0[2],a0[2],qv); qv = fmaf(a0[3],a0[3],qv);
      qv = fmaf(a1[0],a1[0],qv); qv = fmaf(a1[1],a1[1],qv);
      qv = fmaf(a1[2],a1[2],qv); qv = fmaf(a1[3],a1[3],qv);
      sqacc[nt] += qv;
      if (lane < 16){
        maxb[(size_t)g*128 + nt*16 + lane] = mx;
        minb[(size_t)g*128 + nt*16 + lane] = mn;
      }
    }
  }
  #pragma unroll
  for (int nt=0;nt<8;nt++){
    float s = sumacc[nt]; s += __shfl_xor(s,16,64); s += __shfl_xor(s,32,64);
    float qv = sqacc[nt]; qv += __shfl_xor(qv,16,64); qv += __shfl_xor(qv,32,64);
    if (lane < 16){
      atomicAdd(&red[nt*16+lane], s);
      atomicAdd(&red[128+nt*16+lane], qv);
    }
  }
  __syncthreads();
  atomicAdd(&ws[OFF_S2SUM + tid], red[tid]);
}

__global__ __launch_bounds__(256) void final_out_kernel(
    const float* __restrict__ g2, const float* __restrict__ t2,
    const float* __restrict__ ws, float* __restrict__ out)
{
  const int g = blockIdx.x*256 + threadIdx.x; // B*S*128 threads
  const int o = g & 127;
  const float Mf = (float)MPTS;
  float mean = ws[OFF_S2SUM+o] / Mf;
  float var  = ws[OFF_S2SQ+o] / Mf - mean*mean;
  float sc = g2[o] / sqrtf(var + EPSF);
  float sh = t2[o] - mean*sc;
  float v = (sc > 0.f) ? ws[OFF_MAXB+g] : ws[OFF_MINB+g];
  out[BB*SS*3 + g] = fmaxf(fmaf(sc, v, sh), 0.f);
}

extern "C" void kernel_launch(void* const* d_in, const int* in_sizes, int n_in,
                              void* d_out, int out_size, void* d_ws, size_t ws_size,
                              hipStream_t stream)
{
  const float* xyz = (const float*)d_in[0];
  const float* pts = (const float*)d_in[1];
  const int*   fps = (const int*)d_in[2];
  const float* w0  = (const float*)d_in[3];
  const float* b0  = (const float*)d_in[4];
  const float* g0  = (const float*)d_in[5];
  const float* t0  = (const float*)d_in[6];
  const float* w1  = (const float*)d_in[7];
  const float* b1  = (const float*)d_in[8];
  const float* g1  = (const float*)d_in[9];
  const float* t1  = (const float*)d_in[10];
  const float* w2  = (const float*)d_in[11];
  const float* b2  = (const float*)d_in[12];
  const float* g2  = (const float*)d_in[13];
  const float* t2  = (const float*)d_in[14];
  float* out = (float*)d_out;
  float* ws  = (float*)d_ws;

  hipMemsetAsync((void*)(ws + OFF_ST), 0, 512*sizeof(float), stream);
  prep_kernel<<<320,256,0,stream>>>(xyz, fps, out, ws);
  knn_group_kernel<<<BB*SS,256,0,stream>>>(pts, ws);
  mom2_kernel<<<27*8,256,0,stream>>>(ws);
  l1_mfma_kernel<<<512,256,0,stream>>>(w0,b0,g0,t0,w1,b1,ws);
  l2_mfma_kernel<<<1024,256,0,stream>>>(w2,b2,g1,t1,ws);
  final_out_kernel<<<(BB*SS*128)/256,256,0,stream>>>(g2,t2,ws,out);
}

// Round 15
// 218.900 us; speedup vs baseline: 1.1965x; 1.1965x over previous
//
#include <hip/hip_runtime.h>

#define BB 16
#define NN 4096
#define SS 1024
#define KK 32
#define MPTS (BB*SS*KK)      // 524288
#define EPSF 1e-5f
#define CANDCAP 512
#define NARROW 48

// workspace layout (float offsets)
#define OFF_QP    0                       // B*S*4
#define OFF_P4    (OFF_QP + BB*SS*4)      // B*N*4
#define OFF_ST    (OFF_P4 + BB*NN*4)      // 512 floats zeroed each call
#define OFF_MOM   (OFF_ST)                // 27
#define OFF_S1SUM (OFF_ST+32)             // 64
#define OFF_S1SQ  (OFF_ST+96)             // 64
#define OFF_S2SUM (OFF_ST+160)            // 128
#define OFF_S2SQ  (OFF_ST+288)            // 128
#define OFF_XG    (OFF_ST+1280)           // 6*MPTS channel-major
#define OFF_MAXB  (OFF_XG + 6*MPTS)       // B*S*128
#define OFF_MINB  (OFF_MAXB + BB*SS*128)  // B*S*128
#define OFF_Y1U   (OFF_MINB + BB*SS*128)  // bf16 (ushort) POINT-major [MPTS][64]

typedef __bf16 bf16x8 __attribute__((ext_vector_type(8)));
typedef float f32x4 __attribute__((ext_vector_type(4)));
typedef unsigned int uintx4 __attribute__((ext_vector_type(4)));

__device__ __forceinline__ unsigned rne_bf16(float f){
  unsigned u = __float_as_uint(f);
  return (u + 0x7FFFu + ((u>>16)&1u)) >> 16;   // RNE f32->bf16 (finite, non-NaN)
}

__device__ __forceinline__ float pow15(float v){   // v^1.5, v clamped >= ~0
  return exp2f(1.5f * log2f(fmaxf(v, 1e-30f)));
}

__global__ __launch_bounds__(256) void prep_kernel(
    const float* __restrict__ xyz, const int* __restrict__ fps,
    float* __restrict__ out, float* __restrict__ ws)
{
  const int g = blockIdx.x*256 + threadIdx.x;
  if (g < BB*NN){
    const float* p = xyz + (size_t)g*3;
    float x=p[0], y=p[1], z=p[2];
    float x2 = __fadd_rn(__fadd_rn(__fmul_rn(x,x),__fmul_rn(y,y)),__fmul_rn(z,z));
    *reinterpret_cast<float4*>(ws + OFF_P4 + (size_t)g*4) = make_float4(x,y,z,x2);
  } else {
    int j = g - BB*NN;
    if (j < BB*SS){
      int b = j >> 10;
      int idx = fps[j];
      const float* p = xyz + ((size_t)b*NN + idx)*3;
      float x=p[0], y=p[1], z=p[2];
      out[(size_t)j*3+0]=x; out[(size_t)j*3+1]=y; out[(size_t)j*3+2]=z;
      float q2 = __fadd_rn(__fadd_rn(__fmul_rn(x,x),__fmul_rn(y,y)),__fmul_rn(z,z));
      *reinterpret_cast<float4*>(ws + OFF_QP + (size_t)j*4) = make_float4(x,y,z,q2);
    }
  }
}

// one block per query: exact 32-NN. BLOCK-level threshold search with
// origin-anchored power-law interpolation: in 3D, count(<v) = A + B*v^1.5
// (v = squared distance), fit through both bracket anchors -> probe
// mid = ((K-clo)*(hi^1.5-lo^1.5)/(chi-clo) + lo^1.5)^(2/3). ~3-6 rounds
// (bisection fallback after 10, cap 20), 1 barrier/round (double-buffered
// count slots). Invariant count(<lo) < KK <= count(<hi) every round ->
// all keys < hi form a superset (m = chi < 80 on normal exit); exact
// rank-select on packed (key<<32|idx) reproduces top_k's lowest-index ties.
__global__ __launch_bounds__(256) void knn_group_kernel(
    const float* __restrict__ pts, float* __restrict__ ws)
{
  __shared__ unsigned wcnt[2][4];
  __shared__ float wmm[4][2];
  __shared__ unsigned long long cand[CANDCAP];
  __shared__ int sel[KK];
  __shared__ unsigned sh_mcnt;

  const int bid = blockIdx.x;
  const int b = bid >> 10;
  const int tid = threadIdx.x;
  const int lane = tid & 63;
  const int wv = tid >> 6;

  const float4 q = *reinterpret_cast<const float4*>(ws + OFF_QP + (size_t)bid*4);
  const float qx=q.x, qy=q.y, qz=q.z, q2=q.w;
  const float4* pb = reinterpret_cast<const float4*>(ws + OFF_P4) + (size_t)b*NN;

  float d[16];               // static-indexed only (all loops unrolled)
  #pragma unroll
  for (int j=0;j<16;j++){
    int n = tid + j*256;
    float4 P = pb[n];
    float dot = __fadd_rn(__fadd_rn(__fmul_rn(qx,P.x),__fmul_rn(qy,P.y)),__fmul_rn(qz,P.z));
    d[j] = __fsub_rn(__fadd_rn(q2, P.w), __fmul_rn(2.0f,dot));
  }

  if (tid==0) sh_mcnt = 0;

  // block [min,max]
  float mn = d[0], mx = d[0];
  #pragma unroll
  for (int j=1;j<16;j++){ mn = fminf(mn,d[j]); mx = fmaxf(mx,d[j]); }
  #pragma unroll
  for (int off=32; off>=1; off>>=1){
    mn = fminf(mn, __shfl_xor(mn, off, 64));
    mx = fmaxf(mx, __shfl_xor(mx, off, 64));
  }
  if (lane==0){ wmm[wv][0]=mn; wmm[wv][1]=mx; }
  __syncthreads();
  mn = fminf(fminf(wmm[0][0],wmm[1][0]),fminf(wmm[2][0],wmm[3][0]));
  mx = fmaxf(fmaxf(wmm[0][1],wmm[1][1]),fmaxf(wmm[2][1],wmm[3][1]));

  // bracket: count(d < lo) < KK <= count(d < hi)
  float lo = mn, hi = mx*1.0001f + 1e-6f;
  unsigned clo = 0, chi = NN;
  int rounds = 0;
  while (chi - clo > NARROW && rounds < 20){
    float mid;
    if (rounds < 10){
      float pl = pow15(lo), ph = pow15(hi);
      float t = (float)(KK - (int)clo) / (float)(chi - clo);
      float target = fmaf(t, ph - pl, pl);
      mid = exp2f(0.6666667f * log2f(fmaxf(target, 1e-30f)));
    } else {
      mid = 0.5f*(lo + hi);
    }
    if (!(mid > lo && mid < hi)) mid = 0.5f*(lo + hi);
    if (!(mid > lo && mid < hi)) break;     // interval exhausted (ties)
    unsigned cnt = 0;
    #pragma unroll
    for (int j=0;j<16;j++)
      cnt += (unsigned)__popcll(__ballot((int)(d[j] < mid)));
    if (lane==0) wcnt[rounds&1][wv] = cnt;
    __syncthreads();
    const unsigned c = wcnt[rounds&1][0]+wcnt[rounds&1][1]
                     + wcnt[rounds&1][2]+wcnt[rounds&1][3];
    if (c >= (unsigned)KK){ hi = mid; chi = c; } else { lo = mid; clo = c; }
    ++rounds;
  }
  __syncthreads();   // sh_mcnt visible (also covers break-before-any-round)

  // compact: ALL keys < hi are candidates (chi < 80 on normal exit)
  #pragma unroll
  for (int j=0;j<16;j++){
    if (d[j] < hi){
      unsigned u = __float_as_uint(d[j]);
      unsigned key = u ^ (unsigned)(((int)u>>31) | (int)0x80000000);
      unsigned p = atomicAdd(&sh_mcnt,1u);
      if (p < CANDCAP) cand[p] = ((unsigned long long)key<<32) | (unsigned)(tid + j*256);
    }
  }
  __syncthreads();
  const unsigned m = (sh_mcnt < CANDCAP) ? sh_mcnt : CANDCAP;
  // exact rank: (key,idx) lexicographic == packed u64 order (top_k tie rule)
  for (unsigned i=tid; i<m; i+=256){
    const unsigned long long ci = cand[i];
    unsigned r = 0;
    #pragma unroll 4
    for (unsigned jj=0; jj<m; ++jj) r += (cand[jj] < ci) ? 1u : 0u;
    if (r < (unsigned)KK) sel[(int)r] = (int)(ci & 0xFFFFFFFFu);
  }
  __syncthreads();

  // gather the 32 neighbors, write grouped input channel-major
  if (tid < KK){
    int n = sel[tid];
    float4 P = pb[n];
    float v6[6];
    v6[0] = P.x-qx; v6[1] = P.y-qy; v6[2] = P.z-qz;
    const float* pt = pts + ((size_t)b*NN + n)*3;
    v6[3] = pt[0]; v6[4] = pt[1]; v6[5] = pt[2];
    size_t pidx = (size_t)bid*KK + tid;
    float* xg = ws + OFF_XG;
    #pragma unroll
    for (int c=0;c<6;c++) xg[(size_t)c*MPTS + pidx] = v6[c];
  }
}

// layer-0 input moments from the stored grouped input (L3-resident)
__global__ __launch_bounds__(256) void mom2_kernel(float* __restrict__ ws)
{
  static const signed char C1[27]={0,1,2,3,4,5, 0,0,0,0,0,0, 1,1,1,1,1, 2,2,2,2, 3,3,3, 4,4, 5};
  static const signed char C2[27]={-1,-1,-1,-1,-1,-1, 0,1,2,3,4,5, 1,2,3,4,5, 2,3,4,5, 3,4,5, 4,5, 5};
  const int mq = blockIdx.x >> 3;
  const int sl = blockIdx.x & 7;
  const float4* xa = reinterpret_cast<const float4*>(ws + OFF_XG + (size_t)C1[mq]*MPTS) + (size_t)sl*(MPTS/32);
  const int c2 = C2[mq];
  float s = 0.f;
  if (c2 < 0){
    for (int i=threadIdx.x; i<MPTS/32; i+=256){
      float4 a = xa[i];
      s += (a.x+a.y)+(a.z+a.w);
    }
  } else {
    const float4* xb = reinterpret_cast<const float4*>(ws + OFF_XG + (size_t)c2*MPTS) + (size_t)sl*(MPTS/32);
    for (int i=threadIdx.x; i<MPTS/32; i+=256){
      float4 a = xa[i]; float4 bq = xb[i];
      s = fmaf(a.x,bq.x,s); s = fmaf(a.y,bq.y,s);
      s = fmaf(a.z,bq.z,s); s = fmaf(a.w,bq.w,s);
    }
  }
  #pragma unroll
  for (int off=32; off>=1; off>>=1) s += __shfl_xor(s,off,64);
  __shared__ float r[4];
  const int lane = threadIdx.x & 63, wv = threadIdx.x >> 6;
  if (lane==0) r[wv]=s;
  __syncthreads();
  if (threadIdx.x==0) atomicAdd(&ws[OFF_MOM+mq], r[0]+r[1]+r[2]+r[3]);
}

// MFMA layer 1 with finalize0 folded into staging: tid<64 computes BN0-folded
// h0 coefs (swf[c][0..5]=sc*w0, [6]=sc*b0+sh) from the 27 moments.
// D[o][p] = W1[o][c]*h0[c][p]; A=W1 (LDS frag order), B=h0 in-register.
// BN1 stats accumulated in-register, reduced here.
__global__ __launch_bounds__(256) void l1_mfma_kernel(
    const float* __restrict__ w0g, const float* __restrict__ b0g,
    const float* __restrict__ g0, const float* __restrict__ t0,
    const float* __restrict__ w1g, const float* __restrict__ b1g,
    float* __restrict__ ws)
{
  __shared__ __align__(16) unsigned short sA1[4096]; // [mt*2+kt][lane][j]
  __shared__ float swf[64*8];
  __shared__ float red[128];
  const int tid = threadIdx.x;
  const int lane = tid & 63;
  const int wv = tid >> 6;
  const int col = lane & 15;
  const int kg = lane >> 4;

  for (int idx=tid; idx<4096; idx+=256){
    int frag = idx>>9, l = (idx>>3)&63, j = idx&7;
    int mt = frag>>1, kt = frag&1;
    int o = mt*16 + (l&15);
    int c = kt*32 + ((l>>4)<<3) + j;
    sA1[idx] = (unsigned short)rne_bf16(w1g[o*64+c]);
  }
  if (tid<64){
    // finalize0: BN0 scale/shift from input moments, folded into h0 coefs
    const float* mom = ws + OFF_MOM;
    float w[6];
    #pragma unroll
    for (int c=0;c<6;c++) w[c] = w0g[tid*6+c];
    float bo = b0g[tid];
    float wS = 0.f;
    #pragma unroll
    for (int c=0;c<6;c++) wS += w[c]*mom[c];
    const float Mf = (float)MPTS;
    float mean = (wS + Mf*bo) / Mf;
    float qsum = 0.f;
    int mi = 6;
    #pragma unroll
    for (int c=0;c<6;c++){
      #pragma unroll
      for (int c2=c;c2<6;c2++){
        float f = (c==c2)?1.f:2.f;
        qsum += f * w[c]*w[c2]*mom[mi];
        mi++;
      }
    }
    float E2  = (qsum + 2.f*bo*wS + Mf*bo*bo) / Mf;
    float var = E2 - mean*mean;
    float sc  = g0[tid] / sqrtf(var + EPSF);
    float sh  = t0[tid] - mean*sc;
    #pragma unroll
    for (int c=0;c<6;c++) swf[tid*8+c] = sc*w[c];
    swf[tid*8+6] = sc*bo + sh;
    swf[tid*8+7] = 0.f;
  }
  if (tid<128) red[tid]=0.f;
  __syncthreads();

  // folded h0 coefs for this lane's 16 channels (c = kt*32 + kg*8 + j)
  float cw0[2][8], cw1[2][8], cw2[2][8], cw3[2][8], cw4[2][8], cw5[2][8], cb[2][8];
  #pragma unroll
  for (int kt=0; kt<2; ++kt){
    #pragma unroll
    for (int j=0;j<8;j++){
      int c = kt*32 + kg*8 + j;
      float4 a4 = *reinterpret_cast<const float4*>(&swf[c*8]);
      float4 b4 = *reinterpret_cast<const float4*>(&swf[c*8 + 4]);
      cw0[kt][j]=a4.x; cw1[kt][j]=a4.y; cw2[kt][j]=a4.z; cw3[kt][j]=a4.w;
      cw4[kt][j]=b4.x; cw5[kt][j]=b4.y; cb[kt][j]=b4.z;
    }
  }
  float b1v[4][4];
  #pragma unroll
  for (int mt=0;mt<4;mt++)
    #pragma unroll
    for (int r=0;r<4;r++) b1v[mt][r] = b1g[mt*16 + kg*4 + r];

  float s1s[4][4], s1q[4][4];
  #pragma unroll
  for (int mt=0;mt<4;mt++)
    #pragma unroll
    for (int r=0;r<4;r++){ s1s[mt][r]=0.f; s1q[mt][r]=0.f; }

  const float* xg = ws + OFF_XG;
  unsigned short* y1 = (unsigned short*)(ws + OFF_Y1U);
  const int pbase = (blockIdx.x*4 + wv)*256;

  for (int it=0; it<16; ++it){
    const size_t p = (size_t)pbase + it*16 + col;
    const float x0 = xg[p];
    const float x1 = xg[MPTS+p];
    const float x2 = xg[2ul*MPTS+p];
    const float x3 = xg[3ul*MPTS+p];
    const float x4 = xg[4ul*MPTS+p];
    const float x5 = xg[5ul*MPTS+p];

    f32x4 acc0 = {0,0,0,0}, acc1 = {0,0,0,0}, acc2 = {0,0,0,0}, acc3 = {0,0,0,0};

    #pragma unroll
    for (int kt=0; kt<2; ++kt){
      float h[8];
      #pragma unroll
      for (int j=0;j<8;j++){
        float y = cb[kt][j];
        y = fmaf(cw0[kt][j],x0,y); y = fmaf(cw1[kt][j],x1,y);
        y = fmaf(cw2[kt][j],x2,y); y = fmaf(cw3[kt][j],x3,y);
        y = fmaf(cw4[kt][j],x4,y); y = fmaf(cw5[kt][j],x5,y);
        h[j] = fmaxf(y, 0.f);
      }
      uintx4 pk;
      pk[0] = rne_bf16(h[0]) | (rne_bf16(h[1])<<16);
      pk[1] = rne_bf16(h[2]) | (rne_bf16(h[3])<<16);
      pk[2] = rne_bf16(h[4]) | (rne_bf16(h[5])<<16);
      pk[3] = rne_bf16(h[6]) | (rne_bf16(h[7])<<16);
      bf16x8 bfrag = __builtin_bit_cast(bf16x8, pk);
      {
        uintx4 au = *reinterpret_cast<const uintx4*>(&sA1[((0*2+kt)*64+lane)*8]);
        acc0 = __builtin_amdgcn_mfma_f32_16x16x32_bf16(__builtin_bit_cast(bf16x8,au), bfrag, acc0, 0,0,0);
      }
      {
        uintx4 au = *reinterpret_cast<const uintx4*>(&sA1[((1*2+kt)*64+lane)*8]);
        acc1 = __builtin_amdgcn_mfma_f32_16x16x32_bf16(__builtin_bit_cast(bf16x8,au), bfrag, acc1, 0,0,0);
      }
      {
        uintx4 au = *reinterpret_cast<const uintx4*>(&sA1[((2*2+kt)*64+lane)*8]);
        acc2 = __builtin_amdgcn_mfma_f32_16x16x32_bf16(__builtin_bit_cast(bf16x8,au), bfrag, acc2, 0,0,0);
      }
      {
        uintx4 au = *reinterpret_cast<const uintx4*>(&sA1[((3*2+kt)*64+lane)*8]);
        acc3 = __builtin_amdgcn_mfma_f32_16x16x32_bf16(__builtin_bit_cast(bf16x8,au), bfrag, acc3, 0,0,0);
      }
    }
    // epilogue: +b1, stats, pack 4 consecutive o -> uint2, store point-major
    #pragma unroll
    for (int mt=0;mt<4;mt++){
      f32x4 a = (mt==0)?acc0:(mt==1)?acc1:(mt==2)?acc2:acc3;
      float v0 = a[0] + b1v[mt][0];
      float v1 = a[1] + b1v[mt][1];
      float v2 = a[2] + b1v[mt][2];
      float v3 = a[3] + b1v[mt][3];
      s1s[mt][0]+=v0; s1q[mt][0]=fmaf(v0,v0,s1q[mt][0]);
      s1s[mt][1]+=v1; s1q[mt][1]=fmaf(v1,v1,s1q[mt][1]);
      s1s[mt][2]+=v2; s1q[mt][2]=fmaf(v2,v2,s1q[mt][2]);
      s1s[mt][3]+=v3; s1q[mt][3]=fmaf(v3,v3,s1q[mt][3]);
      uint2 st;
      st.x = rne_bf16(v0) | (rne_bf16(v1)<<16);
      st.y = rne_bf16(v2) | (rne_bf16(v3)<<16);
      *reinterpret_cast<uint2*>(y1 + p*64 + mt*16 + kg*4) = st;
    }
  }

  // stats: reduce over the 16 col-lanes (bits 0..3 of lane)
  #pragma unroll
  for (int mt=0;mt<4;mt++){
    #pragma unroll
    for (int r=0;r<4;r++){
      float s = s1s[mt][r], qv = s1q[mt][r];
      s += __shfl_xor(s,1,64); s += __shfl_xor(s,2,64);
      s += __shfl_xor(s,4,64); s += __shfl_xor(s,8,64);
      qv += __shfl_xor(qv,1,64); qv += __shfl_xor(qv,2,64);
      qv += __shfl_xor(qv,4,64); qv += __shfl_xor(qv,8,64);
      if (col==0){
        atomicAdd(&red[mt*16 + kg*4 + r], s);
        atomicAdd(&red[64 + mt*16 + kg*4 + r], qv);
      }
    }
  }
  __syncthreads();
  if (tid < 64){
    atomicAdd(&ws[OFF_S1SUM+tid], red[tid]);
    atomicAdd(&ws[OFF_S1SQ+tid],  red[64+tid]);
  }
}

// MFMA layer 2 with finalize1 folded into staging (tid<64 computes sc1/sh1).
// C[512K x 128] = relu(bn1(Y1))[512K x 64] * W2[64 x 128] + b2.
// A-frag: m=lane&15 (point), k=(lane>>4)*8+j; D: col=lane&15, row=(lane>>4)*4+r.
__global__ __launch_bounds__(256) void l2_mfma_kernel(
    const float* __restrict__ w2g, const float* __restrict__ b2g,
    const float* __restrict__ g1, const float* __restrict__ t1,
    float* __restrict__ ws)
{
  __shared__ __align__(16) unsigned short sB[8192]; // [nt][kt][lane][j]
  __shared__ float s1c[64], s1h[64];
  __shared__ float red[256];
  const int tid = threadIdx.x;
  for (int idx=tid; idx<8192; idx+=256){
    int nt = idx>>10, kt = (idx>>9)&1, l = (idx>>3)&63, j = idx&7;
    int kch = kt*32 + ((l>>4)<<3) + j;
    int o   = (nt<<4) + (l&15);
    sB[idx] = (unsigned short)rne_bf16(w2g[o*64+kch]);
  }
  if (tid<64){
    // finalize1: BN1 scale/shift from y1 stats
    const float Mf = (float)MPTS;
    float mean = ws[OFF_S1SUM+tid]/Mf;
    float var  = ws[OFF_S1SQ+tid]/Mf - mean*mean;
    float sc = g1[tid]/sqrtf(var+EPSF);
    s1c[tid]=sc; s1h[tid]=t1[tid]-mean*sc;
  }
  red[tid]=0.f;
  __syncthreads();

  const int lane = tid & 63;
  const int w    = tid >> 6;
  const int col  = lane & 15;
  const int kg   = lane >> 4;    // 0..3

  float scv[2][8], shv[2][8];
  #pragma unroll
  for (int kt=0;kt<2;kt++)
    #pragma unroll
    for (int j=0;j<8;j++){
      scv[kt][j] = s1c[kt*32 + kg*8 + j];
      shv[kt][j] = s1h[kt*32 + kg*8 + j];
    }
  float b2v[8];
  #pragma unroll
  for (int nt=0;nt<8;nt++) b2v[nt] = b2g[nt*16 + col];

  const unsigned short* y1 = (const unsigned short*)(ws + OFF_Y1U);
  float* maxb = ws + OFF_MAXB;
  float* minb = ws + OFF_MINB;

  float sumacc[8], sqacc[8];
  #pragma unroll
  for (int nt=0;nt<8;nt++){ sumacc[nt]=0.f; sqacc[nt]=0.f; }

  const int gbase = (blockIdx.x*4 + w)*4;
  for (int it=0; it<4; ++it){
    const int g = gbase + it;
    const size_t p0 = (size_t)g*32;
    bf16x8 aA[2][2];
    #pragma unroll
    for (int mh=0; mh<2; ++mh){
      const unsigned short* arow = y1 + (p0 + mh*16 + col)*64 + kg*8;
      #pragma unroll
      for (int kt=0; kt<2; ++kt){
        uintx4 ua = *reinterpret_cast<const uintx4*>(arow + kt*32);
        float h0 = fmaxf(fmaf(scv[kt][0], __uint_as_float(ua[0]<<16),          shv[kt][0]), 0.f);
        float h1 = fmaxf(fmaf(scv[kt][1], __uint_as_float(ua[0]&0xFFFF0000u), shv[kt][1]), 0.f);
        float h2 = fmaxf(fmaf(scv[kt][2], __uint_as_float(ua[1]<<16),          shv[kt][2]), 0.f);
        float h3 = fmaxf(fmaf(scv[kt][3], __uint_as_float(ua[1]&0xFFFF0000u), shv[kt][3]), 0.f);
        float h4 = fmaxf(fmaf(scv[kt][4], __uint_as_float(ua[2]<<16),          shv[kt][4]), 0.f);
        float h5 = fmaxf(fmaf(scv[kt][5], __uint_as_float(ua[2]&0xFFFF0000u), shv[kt][5]), 0.f);
        float h6 = fmaxf(fmaf(scv[kt][6], __uint_as_float(ua[3]<<16),          shv[kt][6]), 0.f);
        float h7 = fmaxf(fmaf(scv[kt][7], __uint_as_float(ua[3]&0xFFFF0000u), shv[kt][7]), 0.f);
        uintx4 pk;
        pk[0] = rne_bf16(h0) | (rne_bf16(h1)<<16);
        pk[1] = rne_bf16(h2) | (rne_bf16(h3)<<16);
        pk[2] = rne_bf16(h4) | (rne_bf16(h5)<<16);
        pk[3] = rne_bf16(h6) | (rne_bf16(h7)<<16);
        aA[mh][kt] = __builtin_bit_cast(bf16x8, pk);
      }
    }
    f32x4 acc[2][8];
    #pragma unroll
    for (int mh=0;mh<2;mh++)
      #pragma unroll
      for (int nt=0;nt<8;nt++){
        f32x4 z = {b2v[nt], b2v[nt], b2v[nt], b2v[nt]};
        acc[mh][nt] = z;
      }
    #pragma unroll
    for (int nt=0;nt<8;nt++){
      #pragma unroll
      for (int kt=0;kt<2;kt++){
        uintx4 bu = *reinterpret_cast<const uintx4*>(&sB[((nt*2+kt)*64 + lane)*8]);
        bf16x8 bv = __builtin_bit_cast(bf16x8, bu);
        acc[0][nt] = __builtin_amdgcn_mfma_f32_16x16x32_bf16(aA[0][kt], bv, acc[0][nt], 0,0,0);
        acc[1][nt] = __builtin_amdgcn_mfma_f32_16x16x32_bf16(aA[1][kt], bv, acc[1][nt], 0,0,0);
      }
    }
    #pragma unroll
    for (int nt=0;nt<8;nt++){
      f32x4 a0 = acc[0][nt], a1 = acc[1][nt];
      float mx = fmaxf(fmaxf(fmaxf(a0[0],a0[1]),fmaxf(a0[2],a0[3])),
                       fmaxf(fmaxf(a1[0],a1[1]),fmaxf(a1[2],a1[3])));
      float mn = fminf(fminf(fminf(a0[0],a0[1]),fminf(a0[2],a0[3])),
                       fminf(fminf(a1[0],a1[1]),fminf(a1[2],a1[3])));
      mx = fmaxf(mx, __shfl_xor(mx,16,64)); mx = fmaxf(mx, __shfl_xor(mx,32,64));
      mn = fminf(mn, __shfl_xor(mn,16,64)); mn = fminf(mn, __shfl_xor(mn,32,64));
      float s = ((a0[0]+a0[1])+(a0[2]+a0[3])) + ((a1[0]+a1[1])+(a1[2]+a1[3]));
      sumacc[nt] += s;
      float qv = 0.f;
      qv = fmaf(a0[0],a0[0],qv); qv = fmaf(a0[1],a0[1],qv);
      qv = fmaf(a0[2],a0[2],qv); qv = fmaf(a0[3],a0[3],qv);
      qv = fmaf(a1[0],a1[0],qv); qv = fmaf(a1[1],a1[1],qv);
      qv = fmaf(a1[2],a1[2],qv); qv = fmaf(a1[3],a1[3],qv);
      sqacc[nt] += qv;
      if (lane < 16){
        maxb[(size_t)g*128 + nt*16 + lane] = mx;
        minb[(size_t)g*128 + nt*16 + lane] = mn;
      }
    }
  }
  #pragma unroll
  for (int nt=0;nt<8;nt++){
    float s = sumacc[nt]; s += __shfl_xor(s,16,64); s += __shfl_xor(s,32,64);
    float qv = sqacc[nt]; qv += __shfl_xor(qv,16,64); qv += __shfl_xor(qv,32,64);
    if (lane < 16){
      atomicAdd(&red[nt*16+lane], s);
      atomicAdd(&red[128+nt*16+lane], qv);
    }
  }
  __syncthreads();
  atomicAdd(&ws[OFF_S2SUM + tid], red[tid]);
}

__global__ __launch_bounds__(256) void final_out_kernel(
    const float* __restrict__ g2, const float* __restrict__ t2,
    const float* __restrict__ ws, float* __restrict__ out)
{
  const int g = blockIdx.x*256 + threadIdx.x; // B*S*128 threads
  const int o = g & 127;
  const float Mf = (float)MPTS;
  float mean = ws[OFF_S2SUM+o] / Mf;
  float var  = ws[OFF_S2SQ+o] / Mf - mean*mean;
  float sc = g2[o] / sqrtf(var + EPSF);
  float sh = t2[o] - mean*sc;
  float v = (sc > 0.f) ? ws[OFF_MAXB+g] : ws[OFF_MINB+g];
  out[BB*SS*3 + g] = fmaxf(fmaf(sc, v, sh), 0.f);
}

extern "C" void kernel_launch(void* const* d_in, const int* in_sizes, int n_in,
                              void* d_out, int out_size, void* d_ws, size_t ws_size,
                              hipStream_t stream)
{
  const float* xyz = (const float*)d_in[0];
  const float* pts = (const float*)d_in[1];
  const int*   fps = (const int*)d_in[2];
  const float* w0  = (const float*)d_in[3];
  const float* b0  = (const float*)d_in[4];
  const float* g0  = (const float*)d_in[5];
  const float* t0  = (const float*)d_in[6];
  const float* w1  = (const float*)d_in[7];
  const float* b1  = (const float*)d_in[8];
  const float* g1  = (const float*)d_in[9];
  const float* t1  = (const float*)d_in[10];
  const float* w2  = (const float*)d_in[11];
  const float* b2  = (const float*)d_in[12];
  const float* g2  = (const float*)d_in[13];
  const float* t2  = (const float*)d_in[14];
  float* out = (float*)d_out;
  float* ws  = (float*)d_ws;

  hipMemsetAsync((void*)(ws + OFF_ST), 0, 512*sizeof(float), stream);
  prep_kernel<<<320,256,0,stream>>>(xyz, fps, out, ws);
  knn_group_kernel<<<BB*SS,256,0,stream>>>(pts, ws);
  mom2_kernel<<<27*8,256,0,stream>>>(ws);
  l1_mfma_kernel<<<512,256,0,stream>>>(w0,b0,g0,t0,w1,b1,ws);
  l2_mfma_kernel<<<1024,256,0,stream>>>(w2,b2,g1,t1,ws);
  final_out_kernel<<<(BB*SS*128)/256,256,0,stream>>>(g2,t2,ws,out);
}